// Round 1
// baseline (13274.507 us; speedup 1.0000x reference)
//
#include <hip/hip_runtime.h>

typedef __attribute__((ext_vector_type(8))) short short8;
typedef __attribute__((ext_vector_type(4))) float f32x4;
typedef __attribute__((ext_vector_type(4))) float float4v;
typedef __attribute__((ext_vector_type(4))) unsigned short u16x4;

#define T_TOT   1024
#define BATCH   64
#define HID     512
#define G4      2048
#define NBLK    32

static __device__ __forceinline__ unsigned short f2bf(float x) {
  union { float f; unsigned u; } v; v.f = x;
  unsigned r = v.u + 0x7FFFu + ((v.u >> 16) & 1u);
  return (unsigned short)(r >> 16);
}

// ---------------------------------------------------------------- init
__global__ void init_k(const float* __restrict__ h0, const float* __restrict__ c0,
                       unsigned short* __restrict__ hbuf, float* __restrict__ cst,
                       float* __restrict__ hst, unsigned int* __restrict__ fin) {
  const int i = blockIdx.x * 256 + threadIdx.x;
  if (i < T_TOT) fin[i] = 0u;
  if (i < BATCH * HID) {
    const float h = h0[i];
    hbuf[i] = f2bf(h);       // parity-0 buffer holds h_0
    hst[i] = h;
    cst[i] = c0[i];
  }
}

// --------------------------------------------------- xz = x@W_ih^T + b
// A: [M][512] f32 (x chunk), W: [2048][512] f32, out: [M][2048] f32
__global__ __launch_bounds__(256) void xz_gemm(
    const float* __restrict__ A, const float* __restrict__ W,
    const float* __restrict__ bih, const float* __restrict__ bhh,
    float* __restrict__ out) {
  __shared__ unsigned short As[128 * 64];
  __shared__ unsigned short Bs[128 * 64];
  const int tid  = threadIdx.x;
  const int lane = tid & 63;
  const int wid  = tid >> 6;
  const int wm   = (wid >> 1) * 64;
  const int wn   = (wid & 1) * 64;
  const int l15  = lane & 15;
  const int l4   = lane >> 4;
  const long bm  = blockIdx.x;
  const long bn  = blockIdx.y;

  f32x4 acc[4][4];
#pragma unroll
  for (int mt = 0; mt < 4; ++mt)
#pragma unroll
    for (int nt = 0; nt < 4; ++nt) acc[mt][nt] = f32x4{0.f, 0.f, 0.f, 0.f};

  const float* Ab = A + bm * 128 * 512;
  const float* Wb = W + bn * 128 * 512;
  const int r0 = tid >> 4;          // 0..15
  const int cq = (tid & 15) * 4;    // col quad 0..60

  for (int k0 = 0; k0 < 512; k0 += 64) {
#pragma unroll
    for (int pass = 0; pass < 8; ++pass) {
      const int r = pass * 16 + r0;
      const float4v va = *(const float4v*)(Ab + (long)r * 512 + k0 + cq);
      const float4v vb = *(const float4v*)(Wb + (long)r * 512 + k0 + cq);
      u16x4 pa, pb;
#pragma unroll
      for (int j = 0; j < 4; ++j) { pa[j] = f2bf(va[j]); pb[j] = f2bf(vb[j]); }
      const int boff = r * 128 + ((cq * 2) ^ ((r & 7) << 4));   // XOR swizzle
      *(u16x4*)((char*)As + boff) = pa;
      *(u16x4*)((char*)Bs + boff) = pb;
    }
    __syncthreads();
#pragma unroll
    for (int kk = 0; kk < 2; ++kk) {
      short8 af[4], bfv[4];
#pragma unroll
      for (int mt = 0; mt < 4; ++mt) {
        const int row = wm + mt * 16 + l15;
        af[mt] = *(const short8*)((const char*)As + row * 128 +
                                  ((kk * 64 + l4 * 16) ^ ((row & 7) << 4)));
      }
#pragma unroll
      for (int nt = 0; nt < 4; ++nt) {
        const int row = wn + nt * 16 + l15;
        bfv[nt] = *(const short8*)((const char*)Bs + row * 128 +
                                   ((kk * 64 + l4 * 16) ^ ((row & 7) << 4)));
      }
#pragma unroll
      for (int mt = 0; mt < 4; ++mt)
#pragma unroll
        for (int nt = 0; nt < 4; ++nt)
          acc[mt][nt] = __builtin_amdgcn_mfma_f32_16x16x32_bf16(af[mt], bfv[nt], acc[mt][nt], 0, 0, 0);
    }
    __syncthreads();
  }

#pragma unroll
  for (int nt = 0; nt < 4; ++nt) {
    const long gn = bn * 128 + wn + nt * 16 + l15;
    const float bias = bih[gn] + bhh[gn];
#pragma unroll
    for (int mt = 0; mt < 4; ++mt) {
      const long gm0 = bm * 128 + wm + mt * 16 + l4 * 4;
#pragma unroll
      for (int r = 0; r < 4; ++r)
        out[(gm0 + r) * G4 + gn] = acc[mt][nt][r] + bias;
    }
  }
}

// ------------------------------------------------------- recurrent core
// 32 persistent blocks; block b owns hidden units [b*16, b*16+16), all 4 gates.
// Wave w computes gate w: [64 batch x 16 hid] = h[64x512] @ W_hh[w*512+slice]^T
__global__ __launch_bounds__(256, 1) void lstm_steps(
    const float* __restrict__ xz,      // [Tc][64][2048]
    const float* __restrict__ Whh,     // [2048][512]
    const float* __restrict__ alpha_p,
    float* __restrict__ out,           // d_out
    unsigned short* __restrict__ hbuf, // 2 x [64][512] bf16
    float* __restrict__ cst, float* __restrict__ hst,
    unsigned int* fin, int t0, int Tc) {
  const int blk = blockIdx.x;
  const int tid = threadIdx.x;
  const int lane = tid & 63;
  const int wid = tid >> 6;        // gate index
  const int hs0 = blk * 16;
  const int l15 = lane & 15;
  const int l4  = lane >> 4;

  __shared__ float gates[4][BATCH][17];   // +1 pad breaks store conflicts
  __shared__ float c_s[BATCH][16];
  __shared__ float h_s[BATCH][16];

  // W_hh fragments -> registers, held for the whole kernel.
  short8 wf[16];
  {
    const float* wr = Whh + (long)(wid * HID + hs0 + l15) * HID + l4 * 8;
#pragma unroll
    for (int ks = 0; ks < 16; ++ks) {
      const float4v lo = *(const float4v*)(wr + ks * 32);
      const float4v hi = *(const float4v*)(wr + ks * 32 + 4);
      short8 f;
#pragma unroll
      for (int j = 0; j < 4; ++j) {
        f[j]     = (short)f2bf(lo[j]);
        f[j + 4] = (short)f2bf(hi[j]);
      }
      wf[ks] = f;
    }
  }
  const float a = alpha_p[0];
  const float oma = 1.0f - a;

  for (int e = tid; e < BATCH * 16; e += 256) {
    const int m = e >> 4, n = e & 15;
    c_s[m][n] = cst[(long)m * HID + hs0 + n];
    h_s[m][n] = hst[(long)m * HID + hs0 + n];
  }
  __syncthreads();

  const long YS = (long)T_TOT * BATCH * HID;

  for (int tt = 0; tt < Tc; ++tt) {
    const int t = t0 + tt;

    // Prefetch xz (gate bias for this step) straight into the accumulator,
    // issued BEFORE the flag wait so HBM latency hides under the spin.
    f32x4 acc[4];
    {
      const float* xzt = xz + (long)tt * BATCH * G4 + wid * HID + hs0 + l15;
#pragma unroll
      for (int mt = 0; mt < 4; ++mt)
#pragma unroll
        for (int r = 0; r < 4; ++r)
          acc[mt][r] = xzt[(long)(mt * 16 + l4 * 4 + r) * G4];
    }

    if (t > 0) {
      if (tid == 0) {
        while (__hip_atomic_load(&fin[t - 1], __ATOMIC_RELAXED,
                                 __HIP_MEMORY_SCOPE_AGENT) < NBLK) {}
      }
      __syncthreads();
      __builtin_amdgcn_fence(__ATOMIC_ACQUIRE, "agent");  // inv L1/L2
    }

    // h_t @ W^T : A-frags straight from the global exchange buffer.
    const unsigned short* hb = hbuf + (size_t)(t & 1) * BATCH * HID;
#pragma unroll
    for (int ks = 0; ks < 16; ++ks) {
#pragma unroll
      for (int mt = 0; mt < 4; ++mt) {
        const short8 af = *(const short8*)(hb + (long)(mt * 16 + l15) * HID + ks * 32 + l4 * 8);
        acc[mt] = __builtin_amdgcn_mfma_f32_16x16x32_bf16(af, wf[ks], acc[mt], 0, 0, 0);
      }
    }
#pragma unroll
    for (int mt = 0; mt < 4; ++mt)
#pragma unroll
      for (int r = 0; r < 4; ++r)
        gates[wid][mt * 16 + l4 * 4 + r][l15] = acc[mt][r];
    __syncthreads();

    unsigned short* hbn = hbuf + (size_t)((t + 1) & 1) * BATCH * HID;
    const bool last = (t == T_TOT - 1);
    for (int e = tid; e < BATCH * 16; e += 256) {
      const int m = e >> 4, n = e & 15;
      const float gi = gates[0][m][n], gf = gates[1][m][n];
      const float gg = gates[2][m][n], go = gates[3][m][n];
      const float ii = 1.0f / (1.0f + __expf(-gi));
      const float ff = 1.0f / (1.0f + __expf(-gf));
      const float g  = tanhf(gg);
      const float oo = 1.0f / (1.0f + __expf(-go));
      const float cp = c_s[m][n], hp = h_s[m][n];
      const float cn = ff * cp + ii * g;
      const float hn = oo * tanhf(cn);
      const float co = a * cn + oma * cp;
      const float ho = a * hn + oma * hp;
      c_s[m][n] = co;
      h_s[m][n] = ho;
      out[((long)t * BATCH + m) * HID + hs0 + n] = ho;          // ys
      hbn[(long)m * HID + hs0 + n] = f2bf(ho);                  // exchange
      if (last) {
        out[YS + (long)m * HID + hs0 + n] = ho;                 // hT
        out[YS + BATCH * HID + (long)m * HID + hs0 + n] = co;   // cT
      }
    }
    __builtin_amdgcn_fence(__ATOMIC_RELEASE, "agent");  // wb L2 -> MALL
    __syncthreads();
    if (tid == 0)
      atomicAdd(&fin[t], 1u);
  }

  __syncthreads();
  for (int e = tid; e < BATCH * 16; e += 256) {
    const int m = e >> 4, n = e & 15;
    cst[(long)m * HID + hs0 + n] = c_s[m][n];
    hst[(long)m * HID + hs0 + n] = h_s[m][n];
  }
}

// ---------------------------------------------------------------- host
extern "C" void kernel_launch(void* const* d_in, const int* in_sizes, int n_in,
                              void* d_out, int out_size, void* d_ws, size_t ws_size,
                              hipStream_t stream) {
  const float* x     = (const float*)d_in[0];
  const float* h0    = (const float*)d_in[1];
  const float* c0    = (const float*)d_in[2];
  const float* W_ih  = (const float*)d_in[3];
  const float* W_hh  = (const float*)d_in[4];
  const float* b_ih  = (const float*)d_in[5];
  const float* b_hh  = (const float*)d_in[6];
  const float* alpha = (const float*)d_in[7];
  float* out = (float*)d_out;

  char* ws = (char*)d_ws;
  unsigned int*  fin  = (unsigned int*)(ws + 0);            //   4 KB
  unsigned short* hbuf = (unsigned short*)(ws + 8192);      // 128 KB
  float* cst = (float*)(ws + 8192 + 131072);                // 128 KB
  float* hst = (float*)(ws + 8192 + 131072 + 131072);       // 128 KB
  float* xzb = (float*)(ws + 524288);                       // Tc*512 KB

  // chunk length: largest power-of-two Tc with (Tc+1)*512KB <= ws_size
  int Tc = T_TOT;
  while ((size_t)(Tc + 1) * 524288ull > ws_size && Tc > 2) Tc >>= 1;

  init_k<<<128, 256, 0, stream>>>(h0, c0, hbuf, cst, hst, fin);
  for (int t0 = 0; t0 < T_TOT; t0 += Tc) {
    dim3 gg(Tc / 2, 16);   // (Tc*64)/128 x 2048/128
    xz_gemm<<<gg, 256, 0, stream>>>(x + (size_t)t0 * BATCH * 512,
                                    W_ih, b_ih, b_hh, xzb);
    lstm_steps<<<NBLK, 256, 0, stream>>>(xzb, W_hh, alpha, out, hbuf,
                                         cst, hst, fin, t0, Tc);
  }
}

// Round 2
// 6392.779 us; speedup vs baseline: 2.0765x; 2.0765x over previous
//
#include <hip/hip_runtime.h>

typedef __attribute__((ext_vector_type(8))) short short8;
typedef __attribute__((ext_vector_type(4))) float f32x4;
typedef __attribute__((ext_vector_type(4))) float float4v;
typedef __attribute__((ext_vector_type(4))) unsigned short u16x4;

#define T_TOT   1024
#define BATCH   64
#define HID     512
#define G4      2048
#define NBLK    32

static __device__ __forceinline__ unsigned short f2bf(float x) {
  union { float f; unsigned u; } v; v.f = x;
  unsigned r = v.u + 0x7FFFu + ((v.u >> 16) & 1u);
  return (unsigned short)(r >> 16);
}

// ---------------------------------------------------------------- init
__global__ void init_k(const float* __restrict__ h0, const float* __restrict__ c0,
                       unsigned short* __restrict__ hbuf, float* __restrict__ cst,
                       float* __restrict__ hst, unsigned int* __restrict__ fin) {
  const int i = blockIdx.x * 256 + threadIdx.x;
  if (i < T_TOT * NBLK) fin[i] = 0u;
  if (i < BATCH * HID) {
    const float h = h0[i];
    hbuf[i] = f2bf(h);       // parity-0 buffer holds h_0
    hst[i] = h;
    cst[i] = c0[i];
  }
}

// --------------------------------------------------- xz = x@W_ih^T + b
__global__ __launch_bounds__(256) void xz_gemm(
    const float* __restrict__ A, const float* __restrict__ W,
    const float* __restrict__ bih, const float* __restrict__ bhh,
    float* __restrict__ out) {
  __shared__ unsigned short As[128 * 64];
  __shared__ unsigned short Bs[128 * 64];
  const int tid  = threadIdx.x;
  const int lane = tid & 63;
  const int wid  = tid >> 6;
  const int wm   = (wid >> 1) * 64;
  const int wn   = (wid & 1) * 64;
  const int l15  = lane & 15;
  const int l4   = lane >> 4;
  const long bm  = blockIdx.x;
  const long bn  = blockIdx.y;

  f32x4 acc[4][4];
#pragma unroll
  for (int mt = 0; mt < 4; ++mt)
#pragma unroll
    for (int nt = 0; nt < 4; ++nt) acc[mt][nt] = f32x4{0.f, 0.f, 0.f, 0.f};

  const float* Ab = A + bm * 128 * 512;
  const float* Wb = W + bn * 128 * 512;
  const int r0 = tid >> 4;
  const int cq = (tid & 15) * 4;

  for (int k0 = 0; k0 < 512; k0 += 64) {
#pragma unroll
    for (int pass = 0; pass < 8; ++pass) {
      const int r = pass * 16 + r0;
      const float4v va = *(const float4v*)(Ab + (long)r * 512 + k0 + cq);
      const float4v vb = *(const float4v*)(Wb + (long)r * 512 + k0 + cq);
      u16x4 pa, pb;
#pragma unroll
      for (int j = 0; j < 4; ++j) { pa[j] = f2bf(va[j]); pb[j] = f2bf(vb[j]); }
      const int boff = r * 128 + ((cq * 2) ^ ((r & 7) << 4));
      *(u16x4*)((char*)As + boff) = pa;
      *(u16x4*)((char*)Bs + boff) = pb;
    }
    __syncthreads();
#pragma unroll
    for (int kk = 0; kk < 2; ++kk) {
      short8 af[4], bfv[4];
#pragma unroll
      for (int mt = 0; mt < 4; ++mt) {
        const int row = wm + mt * 16 + l15;
        af[mt] = *(const short8*)((const char*)As + row * 128 +
                                  ((kk * 64 + l4 * 16) ^ ((row & 7) << 4)));
      }
#pragma unroll
      for (int nt = 0; nt < 4; ++nt) {
        const int row = wn + nt * 16 + l15;
        bfv[nt] = *(const short8*)((const char*)Bs + row * 128 +
                                   ((kk * 64 + l4 * 16) ^ ((row & 7) << 4)));
      }
#pragma unroll
      for (int mt = 0; mt < 4; ++mt)
#pragma unroll
        for (int nt = 0; nt < 4; ++nt)
          acc[mt][nt] = __builtin_amdgcn_mfma_f32_16x16x32_bf16(af[mt], bfv[nt], acc[mt][nt], 0, 0, 0);
    }
    __syncthreads();
  }

#pragma unroll
  for (int nt = 0; nt < 4; ++nt) {
    const long gn = bn * 128 + wn + nt * 16 + l15;
    const float bias = bih[gn] + bhh[gn];
#pragma unroll
    for (int mt = 0; mt < 4; ++mt) {
      const long gm0 = bm * 128 + wm + mt * 16 + l4 * 4;
#pragma unroll
      for (int r = 0; r < 4; ++r)
        out[(gm0 + r) * G4 + gn] = acc[mt][nt][r] + bias;
    }
  }
}

// ------------------------------------------------------- recurrent core
// 32 persistent blocks; block b owns hidden units [b*16, b*16+16), all 4 gates.
// Cross-block exchange via MALL-coherent (agent-scope atomic) accesses only:
// no cache-wide fences. fin[t][blk]==1 published after the block's h-slice
// stores have drained (s_waitcnt vmcnt(0) + barrier) — per-line coherence.
__global__ __launch_bounds__(256, 1) void lstm_steps(
    const float* __restrict__ xz,      // [Tc][64][2048]
    const float* __restrict__ Whh,     // [2048][512]
    const float* __restrict__ alpha_p,
    float* __restrict__ out,           // d_out
    unsigned short* __restrict__ hbuf, // 2 x [64][512] bf16
    float* __restrict__ cst, float* __restrict__ hst,
    unsigned int* fin,                 // [T_TOT][NBLK]
    int t0, int Tc) {
  const int blk = blockIdx.x;
  const int tid = threadIdx.x;
  const int lane = tid & 63;
  const int wid = tid >> 6;        // gate index
  const int hs0 = blk * 16;
  const int l15 = lane & 15;
  const int l4  = lane >> 4;

  __shared__ __align__(16) unsigned short h_lds[BATCH * HID]; // 64 KB, swizzled
  __shared__ float gates[4][BATCH][17];
  __shared__ float c_s[BATCH][16];
  __shared__ float h_s[BATCH][16];

  // W_hh fragments -> registers for the whole kernel (64 VGPRs).
  short8 wf[16];
  {
    const float* wr = Whh + (long)(wid * HID + hs0 + l15) * HID + l4 * 8;
#pragma unroll
    for (int ks = 0; ks < 16; ++ks) {
      const float4v lo = *(const float4v*)(wr + ks * 32);
      const float4v hi = *(const float4v*)(wr + ks * 32 + 4);
      short8 f;
#pragma unroll
      for (int j = 0; j < 4; ++j) {
        f[j]     = (short)f2bf(lo[j]);
        f[j + 4] = (short)f2bf(hi[j]);
      }
      wf[ks] = f;
    }
  }
  const float a = alpha_p[0];
  const float oma = 1.0f - a;

  for (int e = tid; e < BATCH * 16; e += 256) {
    const int m = e >> 4, n = e & 15;
    c_s[m][n] = cst[(long)m * HID + hs0 + n];
    h_s[m][n] = hst[(long)m * HID + hs0 + n];
  }
  __syncthreads();

  const long YS = (long)T_TOT * BATCH * HID;

  for (int tt = 0; tt < Tc; ++tt) {
    const int t = t0 + tt;

    // xz prefetch straight into the accumulator, before the flag wait.
    f32x4 acc[4];
    {
      const float* xzt = xz + (long)tt * BATCH * G4 + wid * HID + hs0 + l15;
#pragma unroll
      for (int mt = 0; mt < 4; ++mt)
#pragma unroll
        for (int r = 0; r < 4; ++r)
          acc[mt][r] = xzt[(long)(mt * 16 + l4 * 4 + r) * G4];
    }

    // Wait for all 32 producer flags of step t-1 (coherent per-lane loads).
    if (t > 0) {
      const unsigned int* fl = fin + (size_t)(t - 1) * NBLK;
      while (true) {
        const unsigned v = __hip_atomic_load(&fl[lane & 31], __ATOMIC_RELAXED,
                                             __HIP_MEMORY_SCOPE_AGENT);
        if (__all(v != 0)) break;
        __builtin_amdgcn_s_sleep(1);
      }
      asm volatile("" ::: "memory");   // no hoisting of data loads above poll
    }

    // Cooperative coherent stage: h (64KB bf16) -> LDS, XOR-swizzled.
    {
      const unsigned long long* hb64 =
          (const unsigned long long*)(hbuf + (size_t)(t & 1) * BATCH * HID);
#pragma unroll
      for (int half = 0; half < 4; ++half) {
        unsigned long long tmp[8];
#pragma unroll
        for (int i = 0; i < 8; ++i)
          tmp[i] = __hip_atomic_load(&hb64[half * 2048 + i * 256 + tid],
                                     __ATOMIC_RELAXED, __HIP_MEMORY_SCOPE_AGENT);
#pragma unroll
        for (int i = 0; i < 8; ++i) {
          const int o = (half * 2048 + i * 256 + tid) * 8;
          *(unsigned long long*)((char*)h_lds + (o ^ (((o >> 10) & 7) << 4))) = tmp[i];
        }
      }
    }
    __syncthreads();

    // h_t @ W^T from swizzled LDS.
#pragma unroll
    for (int ks = 0; ks < 16; ++ks) {
#pragma unroll
      for (int mt = 0; mt < 4; ++mt) {
        const int r  = mt * 16 + l15;
        const int bc = ks * 64 + l4 * 16;
        const short8 af = *(const short8*)((const char*)h_lds + r * 1024 +
                                           (bc ^ ((r & 7) << 4)));
        acc[mt] = __builtin_amdgcn_mfma_f32_16x16x32_bf16(af, wf[ks], acc[mt], 0, 0, 0);
      }
    }
#pragma unroll
    for (int mt = 0; mt < 4; ++mt)
#pragma unroll
      for (int r = 0; r < 4; ++r)
        gates[wid][mt * 16 + l4 * 4 + r][l15] = acc[mt][r];
    __syncthreads();

    unsigned int* hbn32 =
        (unsigned int*)(hbuf + (size_t)((t + 1) & 1) * BATCH * HID);
    const bool last = (t == T_TOT - 1);
    for (int e = tid; e < BATCH * 8; e += 256) {      // 512 n-pairs
      const int m = e >> 3, n0 = (e & 7) << 1;
      float ho2[2], co2[2];
#pragma unroll
      for (int k = 0; k < 2; ++k) {
        const int n = n0 + k;
        const float gi = gates[0][m][n], gf = gates[1][m][n];
        const float gg = gates[2][m][n], go = gates[3][m][n];
        const float ii = 1.0f / (1.0f + __expf(-gi));
        const float ff = 1.0f / (1.0f + __expf(-gf));
        const float g  = tanhf(gg);
        const float oo = 1.0f / (1.0f + __expf(-go));
        const float cp = c_s[m][n], hp = h_s[m][n];
        const float cn = ff * cp + ii * g;
        const float hn = oo * tanhf(cn);
        co2[k] = a * cn + oma * cp;
        ho2[k] = a * hn + oma * hp;
        c_s[m][n] = co2[k];
        h_s[m][n] = ho2[k];
      }
      const long gidx = (long)m * HID + hs0 + n0;
      const unsigned pk = (unsigned)f2bf(ho2[0]) | ((unsigned)f2bf(ho2[1]) << 16);
      __hip_atomic_store(&hbn32[gidx >> 1], pk, __ATOMIC_RELAXED,
                         __HIP_MEMORY_SCOPE_AGENT);          // coherent exchange
      out[((long)t * BATCH + m) * HID + hs0 + n0]     = ho2[0];
      out[((long)t * BATCH + m) * HID + hs0 + n0 + 1] = ho2[1];
      if (last) {
        out[YS + gidx]     = ho2[0];
        out[YS + gidx + 1] = ho2[1];
        out[YS + BATCH * HID + gidx]     = co2[0];
        out[YS + BATCH * HID + gidx + 1] = co2[1];
      }
    }

    // Publish: all h-slice stores at the MALL before the flag leaves.
    asm volatile("s_waitcnt vmcnt(0)" ::: "memory");
    __syncthreads();
    if (tid == 0)
      __hip_atomic_store(&fin[(size_t)t * NBLK + blk], 1u, __ATOMIC_RELAXED,
                         __HIP_MEMORY_SCOPE_AGENT);
  }

  __syncthreads();
  for (int e = tid; e < BATCH * 16; e += 256) {
    const int m = e >> 4, n = e & 15;
    cst[(long)m * HID + hs0 + n] = c_s[m][n];
    hst[(long)m * HID + hs0 + n] = h_s[m][n];
  }
}

// ---------------------------------------------------------------- host
extern "C" void kernel_launch(void* const* d_in, const int* in_sizes, int n_in,
                              void* d_out, int out_size, void* d_ws, size_t ws_size,
                              hipStream_t stream) {
  const float* x     = (const float*)d_in[0];
  const float* h0    = (const float*)d_in[1];
  const float* c0    = (const float*)d_in[2];
  const float* W_ih  = (const float*)d_in[3];
  const float* W_hh  = (const float*)d_in[4];
  const float* b_ih  = (const float*)d_in[5];
  const float* b_hh  = (const float*)d_in[6];
  const float* alpha = (const float*)d_in[7];
  float* out = (float*)d_out;

  char* ws = (char*)d_ws;
  unsigned int*   fin  = (unsigned int*)(ws + 0);           // 128 KB [T][32]
  unsigned short* hbuf = (unsigned short*)(ws + 131072);    // 128 KB (2 bufs)
  float* cst = (float*)(ws + 262144);                       // 128 KB
  float* hst = (float*)(ws + 393216);                       // 128 KB
  float* xzb = (float*)(ws + 524288);                       // Tc*512 KB

  int Tc = T_TOT;
  while ((size_t)Tc * 524288ull + 524288ull > ws_size && Tc > 2) Tc >>= 1;

  init_k<<<128, 256, 0, stream>>>(h0, c0, hbuf, cst, hst, fin);
  for (int t0 = 0; t0 < T_TOT; t0 += Tc) {
    dim3 gg(Tc / 2, 16);
    xz_gemm<<<gg, 256, 0, stream>>>(x + (size_t)t0 * BATCH * 512,
                                    W_ih, b_ih, b_hh, xzb);
    lstm_steps<<<NBLK, 256, 0, stream>>>(xzb, W_hh, alpha, out, hbuf,
                                         cst, hst, fin, t0, Tc);
  }
}

// Round 3
// 5756.860 us; speedup vs baseline: 2.3059x; 1.1105x over previous
//
#include <hip/hip_runtime.h>

typedef __attribute__((ext_vector_type(8))) short short8;
typedef __attribute__((ext_vector_type(4))) float f32x4;
typedef __attribute__((ext_vector_type(4))) float float4v;
typedef __attribute__((ext_vector_type(4))) unsigned short u16x4;
typedef __attribute__((ext_vector_type(4))) unsigned int u32x4;

#define T_TOT   1024
#define BATCH   64
#define HID     512
#define G4      2048
#define NBLK    32

static __device__ __forceinline__ unsigned short f2bf(float x) {
  union { float f; unsigned u; } v; v.f = x;
  unsigned r = v.u + 0x7FFFu + ((v.u >> 16) & 1u);
  return (unsigned short)(r >> 16);
}

// ---------------------------------------------------------------- init
__global__ void init_k(const float* __restrict__ h0, const float* __restrict__ c0,
                       unsigned short* __restrict__ hbuf, float* __restrict__ cst,
                       float* __restrict__ hst, unsigned int* __restrict__ fin) {
  const int i = blockIdx.x * 256 + threadIdx.x;
  if (i < T_TOT * NBLK) fin[i] = 0u;
  if (i < BATCH * HID) {
    const float h = h0[i];
    hbuf[i] = f2bf(h);       // parity-0 buffer holds h_0
    hst[i] = h;
    cst[i] = c0[i];
  }
}

// --------------------------------------------------- xz = x@W_ih^T + b
__global__ __launch_bounds__(256) void xz_gemm(
    const float* __restrict__ A, const float* __restrict__ W,
    const float* __restrict__ bih, const float* __restrict__ bhh,
    float* __restrict__ out) {
  __shared__ unsigned short As[128 * 64];
  __shared__ unsigned short Bs[128 * 64];
  const int tid  = threadIdx.x;
  const int lane = tid & 63;
  const int wid  = tid >> 6;
  const int wm   = (wid >> 1) * 64;
  const int wn   = (wid & 1) * 64;
  const int l15  = lane & 15;
  const int l4   = lane >> 4;
  const long bm  = blockIdx.x;
  const long bn  = blockIdx.y;

  f32x4 acc[4][4];
#pragma unroll
  for (int mt = 0; mt < 4; ++mt)
#pragma unroll
    for (int nt = 0; nt < 4; ++nt) acc[mt][nt] = f32x4{0.f, 0.f, 0.f, 0.f};

  const float* Ab = A + bm * 128 * 512;
  const float* Wb = W + bn * 128 * 512;
  const int r0 = tid >> 4;
  const int cq = (tid & 15) * 4;

  for (int k0 = 0; k0 < 512; k0 += 64) {
#pragma unroll
    for (int pass = 0; pass < 8; ++pass) {
      const int r = pass * 16 + r0;
      const float4v va = *(const float4v*)(Ab + (long)r * 512 + k0 + cq);
      const float4v vb = *(const float4v*)(Wb + (long)r * 512 + k0 + cq);
      u16x4 pa, pb;
#pragma unroll
      for (int j = 0; j < 4; ++j) { pa[j] = f2bf(va[j]); pb[j] = f2bf(vb[j]); }
      const int boff = r * 128 + ((cq * 2) ^ ((r & 7) << 4));
      *(u16x4*)((char*)As + boff) = pa;
      *(u16x4*)((char*)Bs + boff) = pb;
    }
    __syncthreads();
#pragma unroll
    for (int kk = 0; kk < 2; ++kk) {
      short8 af[4], bfv[4];
#pragma unroll
      for (int mt = 0; mt < 4; ++mt) {
        const int row = wm + mt * 16 + l15;
        af[mt] = *(const short8*)((const char*)As + row * 128 +
                                  ((kk * 64 + l4 * 16) ^ ((row & 7) << 4)));
      }
#pragma unroll
      for (int nt = 0; nt < 4; ++nt) {
        const int row = wn + nt * 16 + l15;
        bfv[nt] = *(const short8*)((const char*)Bs + row * 128 +
                                   ((kk * 64 + l4 * 16) ^ ((row & 7) << 4)));
      }
#pragma unroll
      for (int mt = 0; mt < 4; ++mt)
#pragma unroll
        for (int nt = 0; nt < 4; ++nt)
          acc[mt][nt] = __builtin_amdgcn_mfma_f32_16x16x32_bf16(af[mt], bfv[nt], acc[mt][nt], 0, 0, 0);
    }
    __syncthreads();
  }

#pragma unroll
  for (int nt = 0; nt < 4; ++nt) {
    const long gn = bn * 128 + wn + nt * 16 + l15;
    const float bias = bih[gn] + bhh[gn];
#pragma unroll
    for (int mt = 0; mt < 4; ++mt) {
      const long gm0 = bm * 128 + wm + mt * 16 + l4 * 4;
#pragma unroll
      for (int r = 0; r < 4; ++r)
        out[(gm0 + r) * G4 + gn] = acc[mt][nt][r] + bias;
    }
  }
}

// ------------------------------------------------------- recurrent core
// 32 persistent blocks; block b owns hidden units [b*16, b*16+16), all 4 gates.
// Exchange via MALL-coherent (sc0 sc1) loads/stores only; per-block flag
// published after the 2KB h'-slice stores drain. ys/hT/cT stores issue AFTER
// the flag (off the critical path).
__global__ __launch_bounds__(256, 1) void lstm_steps(
    const float* __restrict__ xz,      // [Tc][64][2048]
    const float* __restrict__ Whh,     // [2048][512]
    const float* __restrict__ alpha_p,
    float* __restrict__ out,           // d_out
    unsigned short* __restrict__ hbuf, // 2 x [64][512] bf16
    float* __restrict__ cst, float* __restrict__ hst,
    unsigned int* fin,                 // [T_TOT][NBLK]
    int t0, int Tc) {
  const int blk = blockIdx.x;
  const int tid = threadIdx.x;
  const int lane = tid & 63;
  const int wid = tid >> 6;        // gate index
  const int hs0 = blk * 16;
  const int l15 = lane & 15;
  const int l4  = lane >> 4;

  // h staged as 16B chunks, chunk-transposed: LDS chunk = c*64 + (r ^ (c&7)),
  // where global chunk g = r*64 + c  (r = batch row, c = 16B K-chunk).
  // Both ds_write (stage) and ds_read_b128 (MFMA A-frag) sit at the bank floor.
  __shared__ __align__(16) unsigned short h_lds[BATCH * HID]; // 64 KB
  __shared__ __align__(16) float gates[4][BATCH][20];         // 20 KB
  __shared__ __align__(16) float c_s[BATCH][16];
  __shared__ __align__(16) float h_s[BATCH][16];

  // W_hh fragments -> registers for the whole kernel (64 VGPRs).
  short8 wf[16];
  {
    const float* wr = Whh + (long)(wid * HID + hs0 + l15) * HID + l4 * 8;
#pragma unroll
    for (int ks = 0; ks < 16; ++ks) {
      const float4v lo = *(const float4v*)(wr + ks * 32);
      const float4v hi = *(const float4v*)(wr + ks * 32 + 4);
      short8 f;
#pragma unroll
      for (int j = 0; j < 4; ++j) {
        f[j]     = (short)f2bf(lo[j]);
        f[j + 4] = (short)f2bf(hi[j]);
      }
      wf[ks] = f;
    }
  }
  const float a = alpha_p[0];
  const float oma = 1.0f - a;

  const int em = tid >> 2;          // elementwise row 0..63
  const int en = (tid & 3) << 2;    // elementwise col 0,4,8,12
  {
    const float4v cv = *(const float4v*)(cst + (long)em * HID + hs0 + en);
    const float4v hv = *(const float4v*)(hst + (long)em * HID + hs0 + en);
    *(float4v*)&c_s[em][en] = cv;
    *(float4v*)&h_s[em][en] = hv;
  }
  __syncthreads();

  const long YS = (long)T_TOT * BATCH * HID;

  for (int tt = 0; tt < Tc; ++tt) {
    const int t = t0 + tt;

    // xz prefetch straight into the accumulator, before the flag wait.
    f32x4 acc[4];
    {
      const float* xzt = xz + (long)tt * BATCH * G4 + wid * HID + hs0 + l15;
#pragma unroll
      for (int mt = 0; mt < 4; ++mt)
#pragma unroll
        for (int r = 0; r < 4; ++r)
          acc[mt][r] = xzt[(long)(mt * 16 + l4 * 4 + r) * G4];
    }

    // Wait for all 32 producer flags of step t-1 (coherent per-lane loads).
    if (t > 0) {
      const unsigned int* fl = fin + (size_t)(t - 1) * NBLK;
      while (true) {
        const unsigned v = __hip_atomic_load(&fl[lane & 31], __ATOMIC_RELAXED,
                                             __HIP_MEMORY_SCOPE_AGENT);
        if (__all(v != 0)) break;
      }
      asm volatile("" ::: "memory");   // no hoisting of data loads above poll
    }

    // Stage h (64KB) -> LDS: all 16 coherent 16B loads in flight at once.
    {
      const char* hbase = (const char*)(hbuf + (size_t)(t & 1) * BATCH * HID);
      u32x4 sv[16];
#pragma unroll
      for (int i = 0; i < 16; ++i) {
        const void* ap = hbase + (((long)i * 256 + tid) << 4);
        asm volatile("global_load_dwordx4 %0, %1, off sc0 sc1"
                     : "=v"(sv[i]) : "v"(ap));
      }
      asm volatile("s_waitcnt vmcnt(0)" ::: "memory");
#pragma unroll
      for (int i = 0; i < 16; ++i) {
        const int g = i * 256 + tid;
        const int r = g >> 6, c = g & 63;
        const int chunk = c * 64 + (r ^ (c & 7));
        *(u32x4*)((char*)h_lds + (chunk << 4)) = sv[i];
      }
    }
    __syncthreads();

    // h_t @ W^T : A-frags from chunk-transposed LDS (bank-floor reads).
#pragma unroll
    for (int ks = 0; ks < 16; ++ks) {
      const int c  = ks * 4 + l4;
      const int cb = c << 10;
#pragma unroll
      for (int mt = 0; mt < 4; ++mt) {
        const int slot = (mt * 16 + l15) ^ (c & 7);
        const short8 af = *(const short8*)((const char*)h_lds + cb + (slot << 4));
        acc[mt] = __builtin_amdgcn_mfma_f32_16x16x32_bf16(af, wf[ks], acc[mt], 0, 0, 0);
      }
    }
#pragma unroll
    for (int mt = 0; mt < 4; ++mt)
#pragma unroll
      for (int r = 0; r < 4; ++r)
        gates[wid][mt * 16 + l4 * 4 + r][l15] = acc[mt][r];
    __syncthreads();

    // Elementwise: one float4 granule per thread.
    const float4v gi4 = *(const float4v*)&gates[0][em][en];
    const float4v gf4 = *(const float4v*)&gates[1][em][en];
    const float4v gg4 = *(const float4v*)&gates[2][em][en];
    const float4v go4 = *(const float4v*)&gates[3][em][en];
    const float4v cp4 = *(const float4v*)&c_s[em][en];
    const float4v hp4 = *(const float4v*)&h_s[em][en];
    float4v co4, ho4;
#pragma unroll
    for (int j = 0; j < 4; ++j) {
      const float ii = 1.0f / (1.0f + __expf(-gi4[j]));
      const float ff = 1.0f / (1.0f + __expf(-gf4[j]));
      const float g  = tanhf(gg4[j]);
      const float oo = 1.0f / (1.0f + __expf(-go4[j]));
      const float cn = ff * cp4[j] + ii * g;
      const float hn = oo * tanhf(cn);
      co4[j] = a * cn + oma * cp4[j];
      ho4[j] = a * hn + oma * hp4[j];
    }
    *(float4v*)&c_s[em][en] = co4;
    *(float4v*)&h_s[em][en] = ho4;

    // Coherent exchange store (8B packed bf16 x4), drain, then flag.
    {
      unsigned short* hbn = hbuf + (size_t)((t + 1) & 1) * BATCH * HID;
      const unsigned lo = (unsigned)f2bf(ho4[0]) | ((unsigned)f2bf(ho4[1]) << 16);
      const unsigned hi = (unsigned)f2bf(ho4[2]) | ((unsigned)f2bf(ho4[3]) << 16);
      unsigned long long pk = ((unsigned long long)hi << 32) | lo;
      const void* sp = (const char*)hbn + (((long)em * HID + hs0 + en) << 1);
      asm volatile("global_store_dwordx2 %0, %1, off sc0 sc1"
                   :: "v"(sp), "v"(pk) : "memory");
    }
    asm volatile("s_waitcnt vmcnt(0)" ::: "memory");
    __syncthreads();
    if (tid == 0)
      __hip_atomic_store(&fin[(size_t)t * NBLK + blk], 1u, __ATOMIC_RELAXED,
                         __HIP_MEMORY_SCOPE_AGENT);

    // Off-critical-path output stores.
    *(float4v*)(out + ((long)t * BATCH + em) * HID + hs0 + en) = ho4;
    if (t == T_TOT - 1) {
      *(float4v*)(out + YS + (long)em * HID + hs0 + en) = ho4;
      *(float4v*)(out + YS + BATCH * HID + (long)em * HID + hs0 + en) = co4;
    }
  }

  __syncthreads();
  {
    *(float4v*)(cst + (long)em * HID + hs0 + en) = *(const float4v*)&c_s[em][en];
    *(float4v*)(hst + (long)em * HID + hs0 + en) = *(const float4v*)&h_s[em][en];
  }
}

// ---------------------------------------------------------------- host
extern "C" void kernel_launch(void* const* d_in, const int* in_sizes, int n_in,
                              void* d_out, int out_size, void* d_ws, size_t ws_size,
                              hipStream_t stream) {
  const float* x     = (const float*)d_in[0];
  const float* h0    = (const float*)d_in[1];
  const float* c0    = (const float*)d_in[2];
  const float* W_ih  = (const float*)d_in[3];
  const float* W_hh  = (const float*)d_in[4];
  const float* b_ih  = (const float*)d_in[5];
  const float* b_hh  = (const float*)d_in[6];
  const float* alpha = (const float*)d_in[7];
  float* out = (float*)d_out;

  char* ws = (char*)d_ws;
  unsigned int*   fin  = (unsigned int*)(ws + 0);           // 128 KB [T][32]
  unsigned short* hbuf = (unsigned short*)(ws + 131072);    // 128 KB (2 bufs)
  float* cst = (float*)(ws + 262144);                       // 128 KB
  float* hst = (float*)(ws + 393216);                       // 128 KB
  float* xzb = (float*)(ws + 524288);                       // Tc*512 KB

  int Tc = T_TOT;
  while ((size_t)Tc * 524288ull + 524288ull > ws_size && Tc > 2) Tc >>= 1;

  init_k<<<128, 256, 0, stream>>>(h0, c0, hbuf, cst, hst, fin);
  for (int t0 = 0; t0 < T_TOT; t0 += Tc) {
    dim3 gg(Tc / 2, 16);
    xz_gemm<<<gg, 256, 0, stream>>>(x + (size_t)t0 * BATCH * 512,
                                    W_ih, b_ih, b_hh, xzb);
    lstm_steps<<<NBLK, 256, 0, stream>>>(xzb, W_hh, alpha, out, hbuf,
                                         cst, hst, fin, t0, Tc);
  }
}

// Round 4
// 3096.852 us; speedup vs baseline: 4.2865x; 1.8589x over previous
//
#include <hip/hip_runtime.h>

typedef __attribute__((ext_vector_type(8))) short short8;
typedef __attribute__((ext_vector_type(4))) float f32x4;
typedef __attribute__((ext_vector_type(4))) float float4v;
typedef __attribute__((ext_vector_type(4))) unsigned short u16x4;
typedef __attribute__((ext_vector_type(4))) unsigned int u32x4;

#define T_TOT   1024
#define BATCH   64
#define HID     512
#define G4      2048
#define NGRID   128     // 4 batch-tiles x 32 hid-tiles

static __device__ __forceinline__ unsigned short f2bf(float x) {
  union { float f; unsigned u; } v; v.f = x;
  unsigned r = v.u + 0x7FFFu + ((v.u >> 16) & 1u);
  return (unsigned short)(r >> 16);
}
static __device__ __forceinline__ float sigm(float x) {
  return 1.0f / (1.0f + __expf(-x));
}
static __device__ __forceinline__ float tanh_fast(float x) {
  return 1.0f - 2.0f / (__expf(2.0f * x) + 1.0f);
}

// ---------------------------------------------------------------- init
__global__ void init_k(const float* __restrict__ h0, const float* __restrict__ c0,
                       unsigned short* __restrict__ hbuf, float* __restrict__ cst,
                       float* __restrict__ hst, unsigned int* __restrict__ fin) {
  const int i = blockIdx.x * 256 + threadIdx.x;
  if (i < T_TOT * NGRID) fin[i] = 0u;
  if (i < BATCH * HID) {
    const float h = h0[i];
    hbuf[i] = f2bf(h);       // parity-0 buffer holds h_0
    hst[i] = h;
    cst[i] = c0[i];
  }
}

// --------------------------------------------------- xz = x@W_ih^T + b
__global__ __launch_bounds__(256) void xz_gemm(
    const float* __restrict__ A, const float* __restrict__ W,
    const float* __restrict__ bih, const float* __restrict__ bhh,
    float* __restrict__ out) {
  __shared__ unsigned short As[128 * 64];
  __shared__ unsigned short Bs[128 * 64];
  const int tid  = threadIdx.x;
  const int lane = tid & 63;
  const int wid  = tid >> 6;
  const int wm   = (wid >> 1) * 64;
  const int wn   = (wid & 1) * 64;
  const int l15  = lane & 15;
  const int l4   = lane >> 4;
  const long bm  = blockIdx.x;
  const long bn  = blockIdx.y;

  f32x4 acc[4][4];
#pragma unroll
  for (int mt = 0; mt < 4; ++mt)
#pragma unroll
    for (int nt = 0; nt < 4; ++nt) acc[mt][nt] = f32x4{0.f, 0.f, 0.f, 0.f};

  const float* Ab = A + bm * 128 * 512;
  const float* Wb = W + bn * 128 * 512;
  const int r0 = tid >> 4;
  const int cq = (tid & 15) * 4;

  for (int k0 = 0; k0 < 512; k0 += 64) {
#pragma unroll
    for (int pass = 0; pass < 8; ++pass) {
      const int r = pass * 16 + r0;
      const float4v va = *(const float4v*)(Ab + (long)r * 512 + k0 + cq);
      const float4v vb = *(const float4v*)(Wb + (long)r * 512 + k0 + cq);
      u16x4 pa, pb;
#pragma unroll
      for (int j = 0; j < 4; ++j) { pa[j] = f2bf(va[j]); pb[j] = f2bf(vb[j]); }
      const int boff = r * 128 + ((cq * 2) ^ ((r & 7) << 4));
      *(u16x4*)((char*)As + boff) = pa;
      *(u16x4*)((char*)Bs + boff) = pb;
    }
    __syncthreads();
#pragma unroll
    for (int kk = 0; kk < 2; ++kk) {
      short8 af[4], bfv[4];
#pragma unroll
      for (int mt = 0; mt < 4; ++mt) {
        const int row = wm + mt * 16 + l15;
        af[mt] = *(const short8*)((const char*)As + row * 128 +
                                  ((kk * 64 + l4 * 16) ^ ((row & 7) << 4)));
      }
#pragma unroll
      for (int nt = 0; nt < 4; ++nt) {
        const int row = wn + nt * 16 + l15;
        bfv[nt] = *(const short8*)((const char*)Bs + row * 128 +
                                   ((kk * 64 + l4 * 16) ^ ((row & 7) << 4)));
      }
#pragma unroll
      for (int mt = 0; mt < 4; ++mt)
#pragma unroll
        for (int nt = 0; nt < 4; ++nt)
          acc[mt][nt] = __builtin_amdgcn_mfma_f32_16x16x32_bf16(af[mt], bfv[nt], acc[mt][nt], 0, 0, 0);
    }
    __syncthreads();
  }

#pragma unroll
  for (int nt = 0; nt < 4; ++nt) {
    const long gn = bn * 128 + wn + nt * 16 + l15;
    const float bias = bih[gn] + bhh[gn];
#pragma unroll
    for (int mt = 0; mt < 4; ++mt) {
      const long gm0 = bm * 128 + wm + mt * 16 + l4 * 4;
#pragma unroll
      for (int r = 0; r < 4; ++r)
        out[(gm0 + r) * G4 + gn] = acc[mt][nt][r] + bias;
    }
  }
}

// ------------------------------------------------------- recurrent core
// Grid 128 = 4 batch-tiles (mb) x 32 hid-tiles (nb). Block (mb,nb) owns the
// [16 batch x 16 hid] state patch and computes all 4 gates for it.
// Sync is batch-local: block (mb,nb) polls only group mb's 32 flags.
// Exchange via MALL-coherent (sc0 sc1) accesses; no cache-wide fences.
__global__ __launch_bounds__(256, 1) void lstm_steps(
    const float* __restrict__ xz,      // [Tc][64][2048]
    const float* __restrict__ Whh,     // [2048][512]
    const float* __restrict__ alpha_p,
    float* __restrict__ out,           // d_out
    unsigned short* __restrict__ hbuf, // 2 x [64][512] bf16
    float* __restrict__ cst, float* __restrict__ hst,
    unsigned int* fin,                 // [T_TOT][4][32]
    int t0, int Tc) {
  const int bx  = blockIdx.x;
  const int mb  = bx >> 5;         // batch tile 0..3
  const int nb  = bx & 31;         // hid tile 0..31
  const int rb0 = mb * 16;
  const int hs0 = nb * 16;
  const int tid = threadIdx.x;
  const int lane = tid & 63;
  const int wid = tid >> 6;        // gate index
  const int l15 = lane & 15;
  const int l4  = lane >> 4;

  // h rows staged as 16B chunks: LDS slot = c*16 + (r ^ (c&15)),
  // global chunk g = r*64 + c (r = batch row 0..15, c = K-chunk 0..63).
  // Both ds_write_b128 and ds_read_b128 sit at the bank floor.
  __shared__ __align__(16) unsigned short h_lds[16 * HID];   // 16 KB
  __shared__ __align__(16) float gates[4][16][20];
  __shared__ float c_s[16][17];
  __shared__ float h_s[16][17];

  // W_hh fragments: gate wid, hid cols hs0..hs0+15, full K=512 (64 VGPRs).
  short8 wf[16];
  {
    const float* wr = Whh + (long)(wid * HID + hs0 + l15) * HID + l4 * 8;
#pragma unroll
    for (int ks = 0; ks < 16; ++ks) {
      const float4v lo = *(const float4v*)(wr + ks * 32);
      const float4v hi = *(const float4v*)(wr + ks * 32 + 4);
      short8 f;
#pragma unroll
      for (int j = 0; j < 4; ++j) {
        f[j]     = (short)f2bf(lo[j]);
        f[j + 4] = (short)f2bf(hi[j]);
      }
      wf[ks] = f;
    }
  }
  const float a = alpha_p[0];
  const float oma = 1.0f - a;

  const int em = tid >> 4;          // elementwise row 0..15
  const int en = tid & 15;          // elementwise col 0..15
  c_s[em][en] = cst[(long)(rb0 + em) * HID + hs0 + en];
  h_s[em][en] = hst[(long)(rb0 + em) * HID + hs0 + en];
  __syncthreads();

  const long YS = (long)T_TOT * BATCH * HID;

  for (int tt = 0; tt < Tc; ++tt) {
    const int t = t0 + tt;

    // xz prefetch into the accumulator, before the flag wait.
    f32x4 acc;
    {
      const float* xzt = xz + ((long)tt * BATCH + rb0 + l4 * 4) * G4 +
                         wid * HID + hs0 + l15;
#pragma unroll
      for (int r = 0; r < 4; ++r) acc[r] = xzt[(long)r * G4];
    }
    f32x4 acc2 = f32x4{0.f, 0.f, 0.f, 0.f};

    // Wait for group mb's 32 producer flags of step t-1.
    if (t > 0) {
      const unsigned int* fl = fin + ((size_t)(t - 1) * 4 + mb) * 32;
      while (true) {
        const unsigned v = __hip_atomic_load(&fl[lane & 31], __ATOMIC_RELAXED,
                                             __HIP_MEMORY_SCOPE_AGENT);
        if (__all(v != 0)) break;
      }
      asm volatile("" ::: "memory");   // no hoisting of data loads above poll
    }

    // Stage this group's 16 h rows (16KB) -> LDS, all loads in flight at once.
    {
      const char* hbase = (const char*)(hbuf + (size_t)(t & 1) * BATCH * HID) +
                          (long)rb0 * HID * 2;
      u32x4 sv[4];
#pragma unroll
      for (int i = 0; i < 4; ++i) {
        const void* ap = hbase + (((long)i * 256 + tid) << 4);
        asm volatile("global_load_dwordx4 %0, %1, off sc0 sc1"
                     : "=v"(sv[i]) : "v"(ap));
      }
      asm volatile("s_waitcnt vmcnt(0)" ::: "memory");
#pragma unroll
      for (int i = 0; i < 4; ++i) {
        const int g = i * 256 + tid;
        const int r = g >> 6, c = g & 63;
        *(u32x4*)((char*)h_lds + c * 256 + ((r ^ (c & 15)) << 4)) = sv[i];
      }
    }
    __syncthreads();

    // [16 x 16] = h_rows[16 x 512] @ W^T, two interleaved accumulator chains.
#pragma unroll
    for (int ks = 0; ks < 16; ks += 2) {
      const int c0 = ks * 4 + l4;
      const int c1 = c0 + 4;
      const short8 af0 = *(const short8*)((const char*)h_lds + c0 * 256 +
                                          ((l15 ^ (c0 & 15)) << 4));
      const short8 af1 = *(const short8*)((const char*)h_lds + c1 * 256 +
                                          ((l15 ^ (c1 & 15)) << 4));
      acc  = __builtin_amdgcn_mfma_f32_16x16x32_bf16(af0, wf[ks],     acc,  0, 0, 0);
      acc2 = __builtin_amdgcn_mfma_f32_16x16x32_bf16(af1, wf[ks + 1], acc2, 0, 0, 0);
    }
#pragma unroll
    for (int r = 0; r < 4; ++r)
      gates[wid][l4 * 4 + r][l15] = acc[r] + acc2[r];
    __syncthreads();

    // Elementwise: one element per thread.
    const float gi = gates[0][em][en], gf = gates[1][em][en];
    const float gg = gates[2][em][en], go = gates[3][em][en];
    const float ii = sigm(gi), ff = sigm(gf), oo = sigm(go);
    const float g  = tanh_fast(gg);
    const float cp = c_s[em][en], hp = h_s[em][en];
    const float cn = ff * cp + ii * g;
    const float hn = oo * tanh_fast(cn);
    const float co = a * cn + oma * cp;
    const float ho = a * hn + oma * hp;
    c_s[em][en] = co;
    h_s[em][en] = ho;

    // Coherent exchange store (2B), drain, then flag.
    {
      unsigned short* hbn = hbuf + (size_t)((t + 1) & 1) * BATCH * HID;
      const unsigned hv = (unsigned)f2bf(ho);
      const void* sp = (const char*)hbn + (((long)(rb0 + em) * HID + hs0 + en) << 1);
      asm volatile("global_store_short %0, %1, off sc0 sc1"
                   :: "v"(sp), "v"(hv) : "memory");
    }
    asm volatile("s_waitcnt vmcnt(0)" ::: "memory");
    __syncthreads();
    if (tid == 0)
      __hip_atomic_store(&fin[((size_t)t * 4 + mb) * 32 + nb], 1u,
                         __ATOMIC_RELAXED, __HIP_MEMORY_SCOPE_AGENT);

    // Off-critical-path output stores.
    out[((long)t * BATCH + rb0 + em) * HID + hs0 + en] = ho;
    if (t == T_TOT - 1) {
      out[YS + (long)(rb0 + em) * HID + hs0 + en] = ho;
      out[YS + BATCH * HID + (long)(rb0 + em) * HID + hs0 + en] = co;
    }
  }

  // Persist state for the next chunk (each thread owns its patch element).
  cst[(long)(rb0 + em) * HID + hs0 + en] = c_s[em][en];
  hst[(long)(rb0 + em) * HID + hs0 + en] = h_s[em][en];
}

// ---------------------------------------------------------------- host
extern "C" void kernel_launch(void* const* d_in, const int* in_sizes, int n_in,
                              void* d_out, int out_size, void* d_ws, size_t ws_size,
                              hipStream_t stream) {
  const float* x     = (const float*)d_in[0];
  const float* h0    = (const float*)d_in[1];
  const float* c0    = (const float*)d_in[2];
  const float* W_ih  = (const float*)d_in[3];
  const float* W_hh  = (const float*)d_in[4];
  const float* b_ih  = (const float*)d_in[5];
  const float* b_hh  = (const float*)d_in[6];
  const float* alpha = (const float*)d_in[7];
  float* out = (float*)d_out;

  char* ws = (char*)d_ws;
  unsigned int*   fin  = (unsigned int*)(ws + 0);           // 512 KB [T][4][32]
  unsigned short* hbuf = (unsigned short*)(ws + 524288);    // 128 KB (2 bufs)
  float* cst = (float*)(ws + 655360);                       // 128 KB
  float* hst = (float*)(ws + 786432);                       // 128 KB
  float* xzb = (float*)(ws + 917504);                       // Tc*512 KB

  int Tc = T_TOT;
  while ((size_t)Tc * 524288ull + 917504ull > ws_size && Tc > 2) Tc >>= 1;

  init_k<<<512, 256, 0, stream>>>(h0, c0, hbuf, cst, hst, fin);
  for (int t0 = 0; t0 < T_TOT; t0 += Tc) {
    dim3 gg(Tc / 2, 16);
    xz_gemm<<<gg, 256, 0, stream>>>(x + (size_t)t0 * BATCH * 512,
                                    W_ih, b_ih, b_hh, xzb);
    lstm_steps<<<NGRID, 256, 0, stream>>>(xzb, W_hh, alpha, out, hbuf,
                                          cst, hst, fin, t0, Tc);
  }
}